// Round 2
// baseline (511.036 us; speedup 1.0000x reference)
//
#include <hip/hip_runtime.h>
#include <math.h>

// ---------------------------------------------------------------------------
// LTFGW: N=4096, K=16 (k1=17), T=16, NT=16, D=128, OUTER=3, INNER=5.
//
// R2: (a) exploit C1 sparsity (block-uniform nonzero-row mask, ~2.3 rows/node)
//     (b) Sinkhorn entirely via DPP XOR-walks (zero per-iter LDS)
//     (c) fuse c1 gather into main; merge prep kernels. 3 dispatches total.
// ---------------------------------------------------------------------------

#define NN 4096
#define KNB 16
#define K1 17
#define ROWS 20     // c1/K row stride in floats (80B, 16B-aligned)
#define TSTR 344    // per-template K block stride (344%32==24 -> bank spread)
#define TINYF 1e-16f

typedef const __attribute__((address_space(4))) float* c4fp;
typedef const __attribute__((address_space(4))) int*   c4ip;
__device__ __forceinline__ float sload(const float* p){ return *(c4fp)(unsigned long long)p; }
__device__ __forceinline__ int   sloadi(const int* p) { return *(c4ip)(unsigned long long)p; }

template<int CTRL>
__device__ __forceinline__ float dppmov(float x) {
  return __int_as_float(
      __builtin_amdgcn_update_dpp(0, __float_as_int(x), CTRL, 0xF, 0xF, true));
}
// single-shot xor-permutation within 16-lane row (1-2 DPP)
template<int M> __device__ __forceinline__ float quadx(float x) {
  if constexpr (M==0) return x;
  else if constexpr (M==1) return dppmov<0xB1>(x);
  else if constexpr (M==2) return dppmov<0x4E>(x);
  else return dppmov<0x1B>(x);
}
template<int R> __device__ __forceinline__ float xorperm(float x) {
  if constexpr (R < 4)       return quadx<R>(x);
  else if constexpr (R < 8)  return quadx<R^7>(dppmov<0x141>(x));   // xor7
  else if constexpr (R < 12) return quadx<R^8>(dppmov<0x128>(x));   // xor8
  else                       return quadx<R^15>(dppmov<0x140>(x));  // xor15
}
__device__ __forceinline__ float rsum16(float x) {
  x += dppmov<0xB1>(x); x += dppmov<0x4E>(x);
  x += xorperm<4>(x);   x += dppmov<0x128>(x);
  return x;
}
__device__ __forceinline__ float rmin16(float x) {
  x = fminf(x, dppmov<0xB1>(x)); x = fminf(x, dppmov<0x4E>(x));
  x = fminf(x, xorperm<4>(x));   x = fminf(x, dppmov<0x128>(x));
  return x;
}
__device__ __forceinline__ float rmax16(float x) {
  x = fmaxf(x, dppmov<0xB1>(x)); x = fmaxf(x, dppmov<0x4E>(x));
  x = fmaxf(x, xorperm<4>(x));   x = fmaxf(x, dppmov<0x128>(x));
  return x;
}

// cumulative XOR walk: after step r, g holds source-lane l^r value.
#define WSTEP(C, R, ARR) { g = dppmov<C>(g); acc = fmaf(g, ARR[R], acc); }
#define WALK15(ARR) \
  WSTEP(0xB1,1,ARR)  WSTEP(0x1B,2,ARR)  WSTEP(0xB1,3,ARR)  WSTEP(0x141,4,ARR) \
  WSTEP(0xB1,5,ARR)  WSTEP(0x1B,6,ARR)  WSTEP(0xB1,7,ARR)  WSTEP(0x140,8,ARR) \
  WSTEP(0xB1,9,ARR)  WSTEP(0x1B,10,ARR) WSTEP(0xB1,11,ARR) WSTEP(0x141,12,ARR) \
  WSTEP(0xB1,13,ARR) WSTEP(0x1B,14,ARR) WSTEP(0xB1,15,ARR)

// ---------------------------------------------------------------------------
// prep_all: blocks 0..1023 -> xsq (4 rows/block); block 1024 -> scalars.
// ---------------------------------------------------------------------------
__global__ __launch_bounds__(256) void prep_all(
    const float* __restrict__ x, const float* __restrict__ q0,
    const float* __restrict__ templates_, const float* __restrict__ tf,
    const float* __restrict__ alpha0,
    float* __restrict__ xsq, float* __restrict__ qmat, float* __restrict__ cq,
    float* __restrict__ tfsq, float* __restrict__ walpha) {
  int b = blockIdx.x, tid = threadIdx.x;
  if (b < 1024) {
    int n = b*4 + (tid >> 6), lane = tid & 63;
    float2 v = *(const float2*)&x[n*128 + lane*2];
    float s = fmaf(v.x, v.x, v.y*v.y);
    s += __shfl_xor(s,1); s += __shfl_xor(s,2);  s += __shfl_xor(s,4);
    s += __shfl_xor(s,8); s += __shfl_xor(s,16); s += __shfl_xor(s,32);
    if (lane == 0) xsq[n] = s;
    return;
  }
  int t = tid >> 4, l = tid & 15;
  if (tid == 0) walpha[0] = 1.f / (1.f + expf(-alpha0[0]));
  float qr[16]; float mx = -3.0e38f;
#pragma unroll
  for (int m = 0; m < 16; ++m) { qr[m] = q0[t*16+m]; mx = fmaxf(mx, qr[m]); }
  float s = 0.f;
#pragma unroll
  for (int m = 0; m < 16; ++m) { qr[m] = expf(qr[m]-mx); s += qr[m]; }
  float inv = 1.f / s;
  qmat[tid] = qr[l] * inv;
  float c = 0.f;
#pragma unroll
  for (int m = 0; m < 16; ++m) {
    float c2 = templates_[t*256 + l*16 + m];
    c = fmaf(qr[m]*inv, c2*c2, c);
  }
  cq[tid] = c;
  float ts = 0.f;
#pragma unroll
  for (int dq = 0; dq < 32; ++dq) {
    float4 v = *(const float4*)&tf[tid*128 + dq*4];
    ts = fmaf(v.x,v.x,ts); ts = fmaf(v.y,v.y,ts);
    ts = fmaf(v.z,v.z,ts); ts = fmaf(v.w,v.w,ts);
  }
  tfsq[tid] = ts;
}

// ---------------------------------------------------------------------------
// pgemm: P(4096x256) = x(4096x128) @ tf^T(128x256). 64x64 tiles, 4x4/thread.
// ---------------------------------------------------------------------------
__global__ __launch_bounds__(256, 2) void pgemm(const float* __restrict__ x,
                                                const float* __restrict__ tf,
                                                float* __restrict__ P) {
  __shared__ __align__(16) float As[64][68];
  __shared__ __align__(16) float Bs[64][68];
  int tid = threadIdx.x, tx = tid & 15, ty = tid >> 4;
  int r0 = blockIdx.x * 64, c0 = blockIdx.y * 64;
  float acc[4][4] = {};
  for (int h = 0; h < 2; ++h) {
    __syncthreads();
#pragma unroll
    for (int q = 0; q < 4; ++q) {
      int f = tid + 256*q;
      int row = f >> 4, d4 = (f & 15) << 2;
      float4 a = *(const float4*)&x[(r0+row)*128 + h*64 + d4];
      As[d4+0][row]=a.x; As[d4+1][row]=a.y; As[d4+2][row]=a.z; As[d4+3][row]=a.w;
      float4 b = *(const float4*)&tf[(c0+row)*128 + h*64 + d4];
      Bs[d4+0][row]=b.x; Bs[d4+1][row]=b.y; Bs[d4+2][row]=b.z; Bs[d4+3][row]=b.w;
    }
    __syncthreads();
#pragma unroll
    for (int d = 0; d < 64; ++d) {
      float4 a = *(const float4*)&As[d][ty*4];
      float4 b = *(const float4*)&Bs[d][tx*4];
      float av[4]={a.x,a.y,a.z,a.w}, bv[4]={b.x,b.y,b.z,b.w};
#pragma unroll
      for (int i = 0; i < 4; ++i)
#pragma unroll
        for (int j = 0; j < 4; ++j) acc[i][j] = fmaf(av[i], bv[j], acc[i][j]);
    }
  }
#pragma unroll
  for (int i = 0; i < 4; ++i) {
    float4 o; o.x=acc[i][0]; o.y=acc[i][1]; o.z=acc[i][2]; o.w=acc[i][3];
    *(float4*)&P[(r0 + ty*4 + i)*256 + c0 + tx*4] = o;
  }
}

// ---------------------------------------------------------------------------
// main kernel: 1 block / node, 256 thr = 16 templates x 16 cols.
// ---------------------------------------------------------------------------
__global__ __launch_bounds__(256, 4) void ltfgw_main(
    const float* __restrict__ P, const float* __restrict__ xsq,
    const float* __restrict__ tfsq, const float* __restrict__ qmat,
    const float* __restrict__ cq, const float* __restrict__ walpha,
    const int* __restrict__ neighbors, const float* __restrict__ adj,
    const float* __restrict__ templates_, float* __restrict__ out) {
  __shared__ __align__(16) float c1sh[K1 * ROWS];   // 340
  __shared__ float cc1sh[K1];
  __shared__ int   nbssh[K1];
  __shared__ int   masksh;
  __shared__ __align__(16) float Ksh[16 * TSTR];    // 22016 B
  __shared__ float Ush[256];

  const int tid = threadIdx.x;
  const int t = tid >> 4, l = tid & 15;
  const int n = blockIdx.x;

  const float alpha = sload(walpha);
  const float oma = 1.f - alpha;
  const float na2 = -2.f * alpha;

  if (tid < K1) nbssh[tid] = (tid == 0) ? n : neighbors[n*KNB + tid - 1];
  __syncthreads();

  // --- gather C1 = adj[nb x nb] into LDS (289 scattered loads) ---
  for (int e = tid; e < 289; e += 256) {
    int i = e / 17, j = e % 17;
    c1sh[i*ROWS + j] = adj[nbssh[i]*NN + nbssh[j]];
  }
  __syncthreads();

  // --- per-row: cc1 and nonzero flag ---
  bool nzf = false;
  if (tid < K1) {
    float s = 0.f; bool nz = false;
#pragma unroll
    for (int j = 0; j < K1; ++j) {
      float v = c1sh[tid*ROWS + j];
      s = fmaf(v, v, s); nz |= (v != 0.f);
    }
    cc1sh[tid] = s * (1.f/17.f);
    nzf = nz;
  }
  unsigned long long bal = __ballot(nzf);
  if (tid == 0) masksh = (int)(bal & 0x1FFFF);
  __syncthreads();
  const int mask = __builtin_amdgcn_readfirstlane(masksh);

  const float tfsq_l = tfsq[tid];
  const float cq_l   = cq[tid];
  const float q_l    = qmat[tid];

  // Mcol = (1-a)*M + a*cC
  float Mcol[K1];
#pragma unroll
  for (int k = 0; k < K1; ++k) {
    int nb = (k == 0) ? n : sloadi(neighbors + n*KNB + k - 1);
    float xs = sload(xsq + nb);
    float pv = P[nb*256 + tid];
    Mcol[k] = oma*(xs + tfsq_l - 2.f*pv) + alpha*(cc1sh[k] + cq_l);
  }

  // c2reg[r] = -2a * C2[t][l][l^r]
  float c2reg[16];
#pragma unroll
  for (int r = 0; r < 16; ++r)
    c2reg[r] = na2 * templates_[t*256 + l*16 + (l ^ r)];

  // G(j,l) = KU[j] * vm  (KU = Kc*u per column; init = p*q)
  float KU[K1];
#pragma unroll
  for (int j = 0; j < K1; ++j) KU[j] = 1.f/17.f;
  float vm = q_l;

  const int tb = t * TSTR;
  float Kc16 = 0.f, u16 = 0.f, uloc = 0.f;

#pragma unroll 1
  for (int outer = 0; outer < 3; ++outer) {
    // grad rows; only C1-nonzero rows differ from Mcol
    float gr[K1];
    float lo = 3.0e38f, hi = -3.0e38f;
#pragma unroll
    for (int i = 0; i < K1; ++i) {
      float g = Mcol[i];
      if (mask & (1 << i)) {
        const float* r = &c1sh[i*ROWS];
        float4 a = *(const float4*)(r);
        float4 b = *(const float4*)(r+4);
        float4 c = *(const float4*)(r+8);
        float4 d = *(const float4*)(r+12);
        float s;
        s = a.x*KU[0];            s = fmaf(a.y, KU[1], s);
        s = fmaf(a.z, KU[2], s);  s = fmaf(a.w, KU[3], s);
        s = fmaf(b.x, KU[4], s);  s = fmaf(b.y, KU[5], s);
        s = fmaf(b.z, KU[6], s);  s = fmaf(b.w, KU[7], s);
        s = fmaf(c.x, KU[8], s);  s = fmaf(c.y, KU[9], s);
        s = fmaf(c.z, KU[10], s); s = fmaf(c.w, KU[11], s);
        s = fmaf(d.x, KU[12], s); s = fmaf(d.y, KU[13], s);
        s = fmaf(d.z, KU[14], s); s = fmaf(d.w, KU[15], s);
        s = fmaf(r[16], KU[16], s);
        s *= vm;                     // fold v into G
        float gw = s, acc = s * c2reg[0];
        { float g2 = gw;
          { float g = g2; float acc2 = acc; WALK15(c2reg) acc = acc2 + (acc - acc2); (void)g; }
        }
        // (the block above inlines: acc = sum_r c2reg[r]*T1[l^r])
        g += acc;
      }
      gr[i] = g;
      lo = fminf(lo, g); hi = fmaxf(hi, g);
    }
    lo = rmin16(lo); hi = rmax16(hi);
    float eps = 0.1f * (hi - lo) + TINYF;
    float sc = __builtin_amdgcn_rcpf(eps);
#pragma unroll
    for (int i = 0; i < K1; ++i) {
      float kv = __builtin_amdgcn_exp2f((lo - gr[i]) * sc * 1.4426950408889634f);
      Ksh[tb + i*ROWS + l] = kv;      // transpose write (same wave)
      if (i == 16) Kc16 = kv;
    }
    // permuted row/col reads: Krp[r]=K[l][l^r]; Kcp[r]=K[l^r][l]=xor_r(Krp[r])
    float Krp[16], Kcp[16];
#pragma unroll
    for (int r = 0; r < 16; ++r) Krp[r] = Ksh[tb + l*ROWS + (l ^ r)];
    Kcp[0] = Krp[0];
    Kcp[1]=xorperm<1>(Krp[1]);   Kcp[2]=xorperm<2>(Krp[2]);
    Kcp[3]=xorperm<3>(Krp[3]);   Kcp[4]=xorperm<4>(Krp[4]);
    Kcp[5]=xorperm<5>(Krp[5]);   Kcp[6]=xorperm<6>(Krp[6]);
    Kcp[7]=xorperm<7>(Krp[7]);   Kcp[8]=xorperm<8>(Krp[8]);
    Kcp[9]=xorperm<9>(Krp[9]);   Kcp[10]=xorperm<10>(Krp[10]);
    Kcp[11]=xorperm<11>(Krp[11]); Kcp[12]=xorperm<12>(Krp[12]);
    Kcp[13]=xorperm<13>(Krp[13]); Kcp[14]=xorperm<14>(Krp[14]);
    Kcp[15]=xorperm<15>(Krp[15]);

    // Sinkhorn: 5 iters, all in-register (u,v one-per-lane)
    float vcur = 1.f;
#pragma unroll
    for (int it = 0; it < 5; ++it) {
      float g = vcur;
      float acc = g * Krp[0];
      WALK15(Krp)                       // w[l] = sum_j K[l][j] v[j]
      float w16 = rsum16(Kc16 * vcur);  // row 16
      uloc = (1.f/17.f) * __builtin_amdgcn_rcpf(fmaxf(acc, TINYF));
      u16  = (1.f/17.f) * __builtin_amdgcn_rcpf(fmaxf(w16, TINYF));
      g = uloc;
      acc = fmaf(u16, Kc16, g * Kcp[0]);
      WALK15(Kcp)                       // sg[l] = sum_k u[k] K[k][l] + u16*K16l
      vcur = q_l * __builtin_amdgcn_rcpf(fmaxf(acc, TINYF));
    }
    vm = vcur;

    // KU[j] = K[j][l] * u[j]  (K re-read from LDS; u broadcast via LDS)
    Ush[tid] = uloc;
#pragma unroll
    for (int q = 0; q < 4; ++q) {
      float4 uv = *(const float4*)&Ush[t*16 + q*4];
      KU[q*4+0] = Ksh[tb + (q*4+0)*ROWS + l] * uv.x;
      KU[q*4+1] = Ksh[tb + (q*4+1)*ROWS + l] * uv.y;
      KU[q*4+2] = Ksh[tb + (q*4+2)*ROWS + l] * uv.z;
      KU[q*4+3] = Ksh[tb + (q*4+3)*ROWS + l] * uv.w;
    }
    KU[16] = Kc16 * u16;
  }

  // final: out[n,t] = sum_{i,l} (Mcol + delta) * KU[i] * vm
  float acc1 = 0.f;
#pragma unroll
  for (int i = 0; i < K1; ++i) acc1 = fmaf(Mcol[i], KU[i], acc1);
#pragma unroll
  for (int i = 0; i < K1; ++i) {
    if (mask & (1 << i)) {
      const float* r = &c1sh[i*ROWS];
      float4 a = *(const float4*)(r);
      float4 b = *(const float4*)(r+4);
      float4 c = *(const float4*)(r+8);
      float4 d = *(const float4*)(r+12);
      float s;
      s = a.x*KU[0];            s = fmaf(a.y, KU[1], s);
      s = fmaf(a.z, KU[2], s);  s = fmaf(a.w, KU[3], s);
      s = fmaf(b.x, KU[4], s);  s = fmaf(b.y, KU[5], s);
      s = fmaf(b.z, KU[6], s);  s = fmaf(b.w, KU[7], s);
      s = fmaf(c.x, KU[8], s);  s = fmaf(c.y, KU[9], s);
      s = fmaf(c.z, KU[10], s); s = fmaf(c.w, KU[11], s);
      s = fmaf(d.x, KU[12], s); s = fmaf(d.y, KU[13], s);
      s = fmaf(d.z, KU[14], s); s = fmaf(d.w, KU[15], s);
      s = fmaf(r[16], KU[16], s);
      s *= vm;
      float g = s, acc = s * c2reg[0];
      WALK15(c2reg)
      acc1 = fmaf(acc, KU[i], acc1);
    }
  }
  float accout = rsum16(vm * acc1);
  if (l == 0) out[n*16 + t] = accout;
}

// ---------------------------------------------------------------------------
extern "C" void kernel_launch(void* const* d_in, const int* in_sizes, int n_in,
                              void* d_out, int out_size, void* d_ws, size_t ws_size,
                              hipStream_t stream) {
  const float* x          = (const float*)d_in[0];
  const float* adj        = (const float*)d_in[1];
  const int*   neighbors  = (const int*)  d_in[2];
  const float* templates_ = (const float*)d_in[3];
  const float* tfeat      = (const float*)d_in[4];
  const float* q0         = (const float*)d_in[5];
  const float* alpha0     = (const float*)d_in[6];
  float* out = (float*)d_out;

  float* ws     = (float*)d_ws;
  float* P      = ws;                  // 4096*256
  float* xsq    = P + 4096*256;        // 4096
  float* tfsq   = xsq + 4096;          // 256
  float* qmat   = tfsq + 256;          // 256
  float* cq     = qmat + 256;          // 256
  float* walpha = cq + 256;            // 1

  hipLaunchKernelGGL(prep_all, dim3(1025), dim3(256), 0, stream,
                     x, q0, templates_, tfeat, alpha0,
                     xsq, qmat, cq, tfsq, walpha);
  hipLaunchKernelGGL(pgemm, dim3(64, 4), dim3(256), 0, stream, x, tfeat, P);
  hipLaunchKernelGGL(ltfgw_main, dim3(4096), dim3(256), 0, stream,
                     P, xsq, tfsq, qmat, cq, walpha, neighbors,
                     adj, templates_, out);
}

// Round 3
// 480.205 us; speedup vs baseline: 1.0642x; 1.0642x over previous
//
#include <hip/hip_runtime.h>
#include <math.h>

// ---------------------------------------------------------------------------
// LTFGW: N=4096, K=16 (k1=17), T=16, NT=16, D=128, OUTER=3, INNER=5.
//
// R3: R2 structure (C1 sparsity mask, all-DPP Sinkhorn, fused c1 gather)
//     with the register-spill fixed: __launch_bounds__(256,2) so the ~100-reg
//     live set fits the unified VGPR/AGPR file (R2's (256,4) cap of 128
//     caused 1.5 GB of scratch traffic). Newton-refined Sinkhorn rcps.
// ---------------------------------------------------------------------------

#define NN 4096
#define KNB 16
#define K1 17
#define ROWS 20     // c1/K row stride in floats
#define TSTR 344    // per-template K block stride
#define TINYF 1e-16f

typedef const __attribute__((address_space(4))) float* c4fp;
typedef const __attribute__((address_space(4))) int*   c4ip;
__device__ __forceinline__ float sload(const float* p){ return *(c4fp)(unsigned long long)p; }
__device__ __forceinline__ int   sloadi(const int* p) { return *(c4ip)(unsigned long long)p; }

template<int CTRL>
__device__ __forceinline__ float dppmov(float x) {
  return __int_as_float(
      __builtin_amdgcn_update_dpp(0, __float_as_int(x), CTRL, 0xF, 0xF, true));
}
// 0xB1=quad xor1, 0x4E=quad xor2, 0x1B=quad xor3,
// 0x141=row_half_mirror (xor7), 0x140=row_mirror (xor15), 0x128=row_ror:8 (==xor8 on 16)
template<int M> __device__ __forceinline__ float quadx(float x) {
  if constexpr (M==0) return x;
  else if constexpr (M==1) return dppmov<0xB1>(x);
  else if constexpr (M==2) return dppmov<0x4E>(x);
  else return dppmov<0x1B>(x);
}
template<int R> __device__ __forceinline__ float xorperm(float x) {
  if constexpr (R < 4)       return quadx<R>(x);
  else if constexpr (R < 8)  return quadx<R^7>(dppmov<0x141>(x));
  else if constexpr (R < 12) return quadx<R^8>(dppmov<0x128>(x));
  else                       return quadx<R^15>(dppmov<0x140>(x));
}
__device__ __forceinline__ float rsum16(float x) {
  x += dppmov<0xB1>(x); x += dppmov<0x4E>(x);
  x += xorperm<4>(x);   x += dppmov<0x128>(x);
  return x;
}
__device__ __forceinline__ float rmin16(float x) {
  x = fminf(x, dppmov<0xB1>(x)); x = fminf(x, dppmov<0x4E>(x));
  x = fminf(x, xorperm<4>(x));   x = fminf(x, dppmov<0x128>(x));
  return x;
}
__device__ __forceinline__ float rmax16(float x) {
  x = fmaxf(x, dppmov<0xB1>(x)); x = fmaxf(x, dppmov<0x4E>(x));
  x = fmaxf(x, xorperm<4>(x));   x = fmaxf(x, dppmov<0x128>(x));
  return x;
}
// refined reciprocal: one Newton step on v_rcp_f32
__device__ __forceinline__ float rcpn(float x) {
  float r = __builtin_amdgcn_rcpf(x);
  return r * (2.f - x * r);
}

// cumulative XOR walk: after step r, g holds the source value from lane l^r.
#define WSTEP(C, R, ARR) { g = dppmov<C>(g); acc = fmaf(g, ARR[R], acc); }
#define WALK15(ARR) \
  WSTEP(0xB1,1,ARR)  WSTEP(0x1B,2,ARR)  WSTEP(0xB1,3,ARR)  WSTEP(0x141,4,ARR) \
  WSTEP(0xB1,5,ARR)  WSTEP(0x1B,6,ARR)  WSTEP(0xB1,7,ARR)  WSTEP(0x140,8,ARR) \
  WSTEP(0xB1,9,ARR)  WSTEP(0x1B,10,ARR) WSTEP(0xB1,11,ARR) WSTEP(0x141,12,ARR) \
  WSTEP(0xB1,13,ARR) WSTEP(0x1B,14,ARR) WSTEP(0xB1,15,ARR)

// ---------------------------------------------------------------------------
// prep_all: blocks 0..1023 -> xsq (4 rows/block); block 1024 -> scalars.
// ---------------------------------------------------------------------------
__global__ __launch_bounds__(256) void prep_all(
    const float* __restrict__ x, const float* __restrict__ q0,
    const float* __restrict__ templates_, const float* __restrict__ tf,
    const float* __restrict__ alpha0,
    float* __restrict__ xsq, float* __restrict__ qmat, float* __restrict__ cq,
    float* __restrict__ tfsq, float* __restrict__ walpha) {
  int b = blockIdx.x, tid = threadIdx.x;
  if (b < 1024) {
    int n = b*4 + (tid >> 6), lane = tid & 63;
    float2 v = *(const float2*)&x[n*128 + lane*2];
    float s = fmaf(v.x, v.x, v.y*v.y);
    s += __shfl_xor(s,1); s += __shfl_xor(s,2);  s += __shfl_xor(s,4);
    s += __shfl_xor(s,8); s += __shfl_xor(s,16); s += __shfl_xor(s,32);
    if (lane == 0) xsq[n] = s;
    return;
  }
  int t = tid >> 4, l = tid & 15;
  if (tid == 0) walpha[0] = 1.f / (1.f + expf(-alpha0[0]));
  float qr[16]; float mx = -3.0e38f;
#pragma unroll
  for (int m = 0; m < 16; ++m) { qr[m] = q0[t*16+m]; mx = fmaxf(mx, qr[m]); }
  float s = 0.f;
#pragma unroll
  for (int m = 0; m < 16; ++m) { qr[m] = expf(qr[m]-mx); s += qr[m]; }
  float inv = 1.f / s;
  qmat[tid] = qr[l] * inv;
  float c = 0.f;
#pragma unroll
  for (int m = 0; m < 16; ++m) {
    float c2 = templates_[t*256 + l*16 + m];
    c = fmaf(qr[m]*inv, c2*c2, c);
  }
  cq[tid] = c;
  float ts = 0.f;
#pragma unroll
  for (int dq = 0; dq < 32; ++dq) {
    float4 v = *(const float4*)&tf[tid*128 + dq*4];
    ts = fmaf(v.x,v.x,ts); ts = fmaf(v.y,v.y,ts);
    ts = fmaf(v.z,v.z,ts); ts = fmaf(v.w,v.w,ts);
  }
  tfsq[tid] = ts;
}

// ---------------------------------------------------------------------------
// pgemm: P(4096x256) = x(4096x128) @ tf^T(128x256). 64x64 tiles, 4x4/thread.
// ---------------------------------------------------------------------------
__global__ __launch_bounds__(256, 2) void pgemm(const float* __restrict__ x,
                                                const float* __restrict__ tf,
                                                float* __restrict__ P) {
  __shared__ __align__(16) float As[64][68];
  __shared__ __align__(16) float Bs[64][68];
  int tid = threadIdx.x, tx = tid & 15, ty = tid >> 4;
  int r0 = blockIdx.x * 64, c0 = blockIdx.y * 64;
  float acc[4][4] = {};
  for (int h = 0; h < 2; ++h) {
    __syncthreads();
#pragma unroll
    for (int q = 0; q < 4; ++q) {
      int f = tid + 256*q;
      int row = f >> 4, d4 = (f & 15) << 2;
      float4 a = *(const float4*)&x[(r0+row)*128 + h*64 + d4];
      As[d4+0][row]=a.x; As[d4+1][row]=a.y; As[d4+2][row]=a.z; As[d4+3][row]=a.w;
      float4 b = *(const float4*)&tf[(c0+row)*128 + h*64 + d4];
      Bs[d4+0][row]=b.x; Bs[d4+1][row]=b.y; Bs[d4+2][row]=b.z; Bs[d4+3][row]=b.w;
    }
    __syncthreads();
#pragma unroll
    for (int d = 0; d < 64; ++d) {
      float4 a = *(const float4*)&As[d][ty*4];
      float4 b = *(const float4*)&Bs[d][tx*4];
      float av[4]={a.x,a.y,a.z,a.w}, bv[4]={b.x,b.y,b.z,b.w};
#pragma unroll
      for (int i = 0; i < 4; ++i)
#pragma unroll
        for (int j = 0; j < 4; ++j) acc[i][j] = fmaf(av[i], bv[j], acc[i][j]);
    }
  }
#pragma unroll
  for (int i = 0; i < 4; ++i) {
    float4 o; o.x=acc[i][0]; o.y=acc[i][1]; o.z=acc[i][2]; o.w=acc[i][3];
    *(float4*)&P[(r0 + ty*4 + i)*256 + c0 + tx*4] = o;
  }
}

// ---------------------------------------------------------------------------
// main kernel: 1 block / node, 256 thr = 16 templates x 16 cols.
// ---------------------------------------------------------------------------
__global__ __launch_bounds__(256, 2) void ltfgw_main(
    const float* __restrict__ P, const float* __restrict__ xsq,
    const float* __restrict__ tfsq, const float* __restrict__ qmat,
    const float* __restrict__ cq, const float* __restrict__ walpha,
    const int* __restrict__ neighbors, const float* __restrict__ adj,
    const float* __restrict__ templates_, float* __restrict__ out) {
  __shared__ __align__(16) float c1sh[K1 * ROWS];
  __shared__ float cc1sh[K1];
  __shared__ int   nbssh[K1];
  __shared__ int   masksh;
  __shared__ __align__(16) float Ksh[16 * TSTR];
  __shared__ float Ush[256];

  const int tid = threadIdx.x;
  const int t = tid >> 4, l = tid & 15;
  const int n = blockIdx.x;

  const float alpha = sload(walpha);
  const float oma = 1.f - alpha;
  const float na2 = -2.f * alpha;

  if (tid < K1) nbssh[tid] = (tid == 0) ? n : neighbors[n*KNB + tid - 1];
  __syncthreads();

  // gather C1 = adj[nb x nb] into LDS (289 scattered loads, memory pipes idle)
  for (int e = tid; e < 289; e += 256) {
    int i = e / 17, j = e % 17;
    c1sh[i*ROWS + j] = adj[nbssh[i]*NN + nbssh[j]];
  }
  __syncthreads();

  // per-row: cc1 = (1/17)*sum_j C1[i,j]^2, and nonzero-row flag
  bool nzf = false;
  if (tid < K1) {
    float s = 0.f; bool nz = false;
#pragma unroll
    for (int j = 0; j < K1; ++j) {
      float v = c1sh[tid*ROWS + j];
      s = fmaf(v, v, s); nz |= (v != 0.f);
    }
    cc1sh[tid] = s * (1.f/17.f);
    nzf = nz;
  }
  unsigned long long bal = __ballot(nzf);
  if (tid == 0) masksh = (int)(bal & 0x1FFFF);
  __syncthreads();
  const int mask = __builtin_amdgcn_readfirstlane(masksh);

  const float tfsq_l = tfsq[tid];
  const float cq_l   = cq[tid];
  const float q_l    = qmat[tid];

  // Mcol = (1-a)*M + a*cC  (pre-blended; grad = Mcol - 2a*C1@G@C2^T)
  float Mcol[K1];
#pragma unroll
  for (int k = 0; k < K1; ++k) {
    int nb = (k == 0) ? n : sloadi(neighbors + n*KNB + k - 1);
    float xs = sload(xsq + nb);
    float pv = P[nb*256 + tid];
    Mcol[k] = oma*(xs + tfsq_l - 2.f*pv) + alpha*(cc1sh[k] + cq_l);
  }

  // c2reg[r] = -2a * C2[t][l][l^r]  (pre-rotated for XOR walk)
  float c2reg[16];
#pragma unroll
  for (int r = 0; r < 16; ++r)
    c2reg[r] = na2 * templates_[t*256 + l*16 + (l ^ r)];

  // G(j,l) = KU[j] * vm ; init G = p*q
  float KU[K1];
#pragma unroll
  for (int j = 0; j < K1; ++j) KU[j] = 1.f/17.f;
  float vm = q_l;

  const int tb = t * TSTR;
  float Kc16 = 0.f, u16 = 0.f, uloc = 0.f;

#pragma unroll 1
  for (int outer = 0; outer < 3; ++outer) {
    // grad rows; only C1-nonzero rows differ from Mcol
    float gr[K1];
    float lo = 3.0e38f, hi = -3.0e38f;
#pragma unroll
    for (int i = 0; i < K1; ++i) {
      float g = Mcol[i];
      if (mask & (1 << i)) {
        const float* r = &c1sh[i*ROWS];
        float4 a = *(const float4*)(r);
        float4 b = *(const float4*)(r+4);
        float4 c = *(const float4*)(r+8);
        float4 d = *(const float4*)(r+12);
        float s;
        s = a.x*KU[0];            s = fmaf(a.y, KU[1], s);
        s = fmaf(a.z, KU[2], s);  s = fmaf(a.w, KU[3], s);
        s = fmaf(b.x, KU[4], s);  s = fmaf(b.y, KU[5], s);
        s = fmaf(b.z, KU[6], s);  s = fmaf(b.w, KU[7], s);
        s = fmaf(c.x, KU[8], s);  s = fmaf(c.y, KU[9], s);
        s = fmaf(c.z, KU[10], s); s = fmaf(c.w, KU[11], s);
        s = fmaf(d.x, KU[12], s); s = fmaf(d.y, KU[13], s);
        s = fmaf(d.z, KU[14], s); s = fmaf(d.w, KU[15], s);
        s = fmaf(r[16], KU[16], s);
        s *= vm;                  // T1[i][l] (v folded in)
        float gg = s, acc = s * c2reg[0];
        { float g2 = gg; float g = g2; WALK15(c2reg) (void)g; g += acc; }
        g = Mcol[i] + acc;        // delta = sum_r c2reg[r]*T1[i][l^r]
      }
      gr[i] = g;
      lo = fminf(lo, g); hi = fmaxf(hi, g);
    }
    lo = rmin16(lo); hi = rmax16(hi);
    float eps = 0.1f * (hi - lo) + TINYF;
    float sc = 1.4426950408889634f * __builtin_amdgcn_rcpf(eps);
#pragma unroll
    for (int i = 0; i < K1; ++i) {
      float kv = __builtin_amdgcn_exp2f((lo - gr[i]) * sc);
      Ksh[tb + i*ROWS + l] = kv;
      if (i == 16) Kc16 = kv;
    }
    // Krp[r]=K[l][l^r] (row l, permuted); Kcp[r]=K[l^r][l]=xor_r(Krp[r])
    float Krp[16], Kcp[16];
#pragma unroll
    for (int r = 0; r < 16; ++r) Krp[r] = Ksh[tb + l*ROWS + (l ^ r)];
    Kcp[0] = Krp[0];
    Kcp[1]=xorperm<1>(Krp[1]);    Kcp[2]=xorperm<2>(Krp[2]);
    Kcp[3]=xorperm<3>(Krp[3]);    Kcp[4]=xorperm<4>(Krp[4]);
    Kcp[5]=xorperm<5>(Krp[5]);    Kcp[6]=xorperm<6>(Krp[6]);
    Kcp[7]=xorperm<7>(Krp[7]);    Kcp[8]=xorperm<8>(Krp[8]);
    Kcp[9]=xorperm<9>(Krp[9]);    Kcp[10]=xorperm<10>(Krp[10]);
    Kcp[11]=xorperm<11>(Krp[11]); Kcp[12]=xorperm<12>(Krp[12]);
    Kcp[13]=xorperm<13>(Krp[13]); Kcp[14]=xorperm<14>(Krp[14]);
    Kcp[15]=xorperm<15>(Krp[15]);

    // Sinkhorn: 5 iters, all in-register (u,v one value per lane)
    float vcur = 1.f;
#pragma unroll
    for (int it = 0; it < 5; ++it) {
      float g = vcur;
      float acc = g * Krp[0];
      WALK15(Krp)                       // acc = sum_j K[l][j] v[j]
      float w16 = rsum16(Kc16 * vcur);  // row 16
      uloc = (1.f/17.f) * rcpn(fmaxf(acc, TINYF));
      u16  = (1.f/17.f) * rcpn(fmaxf(w16, TINYF));
      g = uloc;
      acc = fmaf(u16, Kc16, g * Kcp[0]);
      WALK15(Kcp)                       // acc = sum_k u[k] K[k][l] (+row16)
      vcur = q_l * rcpn(fmaxf(acc, TINYF));
    }
    vm = vcur;

    // KU[j] = K[j][l] * u[j]
    Ush[tid] = uloc;
#pragma unroll
    for (int q = 0; q < 4; ++q) {
      float4 uv = *(const float4*)&Ush[t*16 + q*4];
      KU[q*4+0] = Ksh[tb + (q*4+0)*ROWS + l] * uv.x;
      KU[q*4+1] = Ksh[tb + (q*4+1)*ROWS + l] * uv.y;
      KU[q*4+2] = Ksh[tb + (q*4+2)*ROWS + l] * uv.z;
      KU[q*4+3] = Ksh[tb + (q*4+3)*ROWS + l] * uv.w;
    }
    KU[16] = Kc16 * u16;
  }

  // final: out[n,t] = sum_{i,l} (Mcol + delta) * KU[i] * vm
  float acc1 = 0.f;
#pragma unroll
  for (int i = 0; i < K1; ++i) acc1 = fmaf(Mcol[i], KU[i], acc1);
#pragma unroll
  for (int i = 0; i < K1; ++i) {
    if (mask & (1 << i)) {
      const float* r = &c1sh[i*ROWS];
      float4 a = *(const float4*)(r);
      float4 b = *(const float4*)(r+4);
      float4 c = *(const float4*)(r+8);
      float4 d = *(const float4*)(r+12);
      float s;
      s = a.x*KU[0];            s = fmaf(a.y, KU[1], s);
      s = fmaf(a.z, KU[2], s);  s = fmaf(a.w, KU[3], s);
      s = fmaf(b.x, KU[4], s);  s = fmaf(b.y, KU[5], s);
      s = fmaf(b.z, KU[6], s);  s = fmaf(b.w, KU[7], s);
      s = fmaf(c.x, KU[8], s);  s = fmaf(c.y, KU[9], s);
      s = fmaf(c.z, KU[10], s); s = fmaf(c.w, KU[11], s);
      s = fmaf(d.x, KU[12], s); s = fmaf(d.y, KU[13], s);
      s = fmaf(d.z, KU[14], s); s = fmaf(d.w, KU[15], s);
      s = fmaf(r[16], KU[16], s);
      s *= vm;
      float g = s, acc = s * c2reg[0];
      WALK15(c2reg)
      acc1 = fmaf(acc, KU[i], acc1);
    }
  }
  float accout = rsum16(vm * acc1);
  if (l == 0) out[n*16 + t] = accout;
}

// ---------------------------------------------------------------------------
extern "C" void kernel_launch(void* const* d_in, const int* in_sizes, int n_in,
                              void* d_out, int out_size, void* d_ws, size_t ws_size,
                              hipStream_t stream) {
  const float* x          = (const float*)d_in[0];
  const float* adj        = (const float*)d_in[1];
  const int*   neighbors  = (const int*)  d_in[2];
  const float* templates_ = (const float*)d_in[3];
  const float* tfeat      = (const float*)d_in[4];
  const float* q0         = (const float*)d_in[5];
  const float* alpha0     = (const float*)d_in[6];
  float* out = (float*)d_out;

  float* ws     = (float*)d_ws;
  float* P      = ws;                  // 4096*256
  float* xsq    = P + 4096*256;        // 4096
  float* tfsq   = xsq + 4096;          // 256
  float* qmat   = tfsq + 256;          // 256
  float* cq     = qmat + 256;          // 256
  float* walpha = cq + 256;            // 1

  hipLaunchKernelGGL(prep_all, dim3(1025), dim3(256), 0, stream,
                     x, q0, templates_, tfeat, alpha0,
                     xsq, qmat, cq, tfsq, walpha);
  hipLaunchKernelGGL(pgemm, dim3(64, 4), dim3(256), 0, stream, x, tfeat, P);
  hipLaunchKernelGGL(ltfgw_main, dim3(4096), dim3(256), 0, stream,
                     P, xsq, tfsq, qmat, cq, walpha, neighbors,
                     adj, templates_, out);
}

// Round 4
// 193.169 us; speedup vs baseline: 2.6455x; 2.4859x over previous
//
#include <hip/hip_runtime.h>
#include <math.h>

// ---------------------------------------------------------------------------
// LTFGW: N=4096, K=16 (k1=17), T=16, NT=16, D=128, OUTER=3, INNER=5.
//
// R4: back to R1's proven skeleton (scalar-pipe C1 via s_load from gathered
//     C1ws, LDS-broadcast Sinkhorn, launch_bounds(256,2), unroll-1 loops)
//     + C1 row-sparsity mask (skip matvec+DPP-walk for all-zero rows)
//     + w16 via DPP rsum (drops kr16[16] regs)
//     + TSTR=296 (2-way-free LDS bank pattern).
// R2/R3 lesson: LDS float4 C1 loads inside 17 unrolled branches let the
// scheduler hoist ~270 VGPRs of ds_read results -> scratch spill (512MB-1GB
// WRITE_SIZE, VALUBusy 18%). Scalar loads keep the vector live set ~100.
// ---------------------------------------------------------------------------

#define NN 4096
#define KNB 16
#define K1 17
#define C1STRIDE 20   // C1 row: 17 vals + cc1@17 + mask@18(row0) + pad
#define C1NODE 340
#define TSTR 296      // Ksh per-template stride; 296%32==8 -> 2-way banks
#define TINYF 1e-16f

typedef const __attribute__((address_space(4))) float* c4fp;
typedef const __attribute__((address_space(4))) int*   c4ip;
__device__ __forceinline__ float sload(const float* p){ return *(c4fp)(unsigned long long)p; }
__device__ __forceinline__ int   sloadi(const int* p) { return *(c4ip)(unsigned long long)p; }

template<int CTRL>
__device__ __forceinline__ float dppmov(float x) {
  return __int_as_float(
      __builtin_amdgcn_update_dpp(0, __float_as_int(x), CTRL, 0xF, 0xF, true));
}
__device__ __forceinline__ float xor4v(float x) {        // xor4 = xor7 then xor3
  return dppmov<0x1B>(dppmov<0x141>(x));
}
__device__ __forceinline__ float rsum16(float x) {
  x += dppmov<0xB1>(x); x += dppmov<0x4E>(x);
  x += xor4v(x);        x += dppmov<0x128>(x);
  return x;
}
__device__ __forceinline__ float rmin16(float x) {
  x = fminf(x, dppmov<0xB1>(x)); x = fminf(x, dppmov<0x4E>(x));
  x = fminf(x, xor4v(x));        x = fminf(x, dppmov<0x128>(x));
  return x;
}
__device__ __forceinline__ float rmax16(float x) {
  x = fmaxf(x, dppmov<0xB1>(x)); x = fmaxf(x, dppmov<0x4E>(x));
  x = fmaxf(x, xor4v(x));        x = fmaxf(x, dppmov<0x128>(x));
  return x;
}
__device__ __forceinline__ float rcpn(float x) {   // rcp + 1 Newton step
  float r = __builtin_amdgcn_rcpf(x);
  return r * (2.f - x * r);
}

// cumulative XOR walk (verified in R1, absmax 0): after step r, g = src lane l^r
#define WSTEP(C, R) { g = dppmov<C>(g); acc = fmaf(g, c2reg[R], acc); }
#define WALK15() \
  WSTEP(0xB1,1)  WSTEP(0x1B,2)  WSTEP(0xB1,3)  WSTEP(0x141,4) \
  WSTEP(0xB1,5)  WSTEP(0x1B,6)  WSTEP(0xB1,7)  WSTEP(0x140,8) \
  WSTEP(0xB1,9)  WSTEP(0x1B,10) WSTEP(0xB1,11) WSTEP(0x141,12) \
  WSTEP(0xB1,13) WSTEP(0x1B,14) WSTEP(0xB1,15)

// ---------------------------------------------------------------------------
// prep_all: blocks 0..1023 -> xsq (4 rows/block); block 1024 -> scalars.
// ---------------------------------------------------------------------------
__global__ __launch_bounds__(256) void prep_all(
    const float* __restrict__ x, const float* __restrict__ q0,
    const float* __restrict__ templates_, const float* __restrict__ tf,
    const float* __restrict__ alpha0,
    float* __restrict__ xsq, float* __restrict__ qmat, float* __restrict__ cq,
    float* __restrict__ tfsq, float* __restrict__ walpha) {
  int b = blockIdx.x, tid = threadIdx.x;
  if (b < 1024) {
    int n = b*4 + (tid >> 6), lane = tid & 63;
    float2 v = *(const float2*)&x[n*128 + lane*2];
    float s = fmaf(v.x, v.x, v.y*v.y);
    s += __shfl_xor(s,1); s += __shfl_xor(s,2);  s += __shfl_xor(s,4);
    s += __shfl_xor(s,8); s += __shfl_xor(s,16); s += __shfl_xor(s,32);
    if (lane == 0) xsq[n] = s;
    return;
  }
  int t = tid >> 4, l = tid & 15;
  if (tid == 0) walpha[0] = 1.f / (1.f + expf(-alpha0[0]));
  float qr[16]; float mx = -3.0e38f;
#pragma unroll
  for (int m = 0; m < 16; ++m) { qr[m] = q0[t*16+m]; mx = fmaxf(mx, qr[m]); }
  float s = 0.f;
#pragma unroll
  for (int m = 0; m < 16; ++m) { qr[m] = expf(qr[m]-mx); s += qr[m]; }
  float inv = 1.f / s;
  qmat[tid] = qr[l] * inv;
  float c = 0.f;
#pragma unroll
  for (int m = 0; m < 16; ++m) {
    float c2 = templates_[t*256 + l*16 + m];
    c = fmaf(qr[m]*inv, c2*c2, c);
  }
  cq[tid] = c;
  float ts = 0.f;
#pragma unroll
  for (int dq = 0; dq < 32; ++dq) {
    float4 v = *(const float4*)&tf[tid*128 + dq*4];
    ts = fmaf(v.x,v.x,ts); ts = fmaf(v.y,v.y,ts);
    ts = fmaf(v.z,v.z,ts); ts = fmaf(v.w,v.w,ts);
  }
  tfsq[tid] = ts;
}

// ---------------------------------------------------------------------------
// pgemm: P(4096x256) = x(4096x128) @ tf^T(128x256). 64x64 tiles, 4x4/thread.
// ---------------------------------------------------------------------------
__global__ __launch_bounds__(256, 2) void pgemm(const float* __restrict__ x,
                                                const float* __restrict__ tf,
                                                float* __restrict__ P) {
  __shared__ __align__(16) float As[64][68];
  __shared__ __align__(16) float Bs[64][68];
  int tid = threadIdx.x, tx = tid & 15, ty = tid >> 4;
  int r0 = blockIdx.x * 64, c0 = blockIdx.y * 64;
  float acc[4][4] = {};
  for (int h = 0; h < 2; ++h) {
    __syncthreads();
#pragma unroll
    for (int q = 0; q < 4; ++q) {
      int f = tid + 256*q;
      int row = f >> 4, d4 = (f & 15) << 2;
      float4 a = *(const float4*)&x[(r0+row)*128 + h*64 + d4];
      As[d4+0][row]=a.x; As[d4+1][row]=a.y; As[d4+2][row]=a.z; As[d4+3][row]=a.w;
      float4 b = *(const float4*)&tf[(c0+row)*128 + h*64 + d4];
      Bs[d4+0][row]=b.x; Bs[d4+1][row]=b.y; Bs[d4+2][row]=b.z; Bs[d4+3][row]=b.w;
    }
    __syncthreads();
#pragma unroll
    for (int d = 0; d < 64; ++d) {
      float4 a = *(const float4*)&As[d][ty*4];
      float4 b = *(const float4*)&Bs[d][tx*4];
      float av[4]={a.x,a.y,a.z,a.w}, bv[4]={b.x,b.y,b.z,b.w};
#pragma unroll
      for (int i = 0; i < 4; ++i)
#pragma unroll
        for (int j = 0; j < 4; ++j) acc[i][j] = fmaf(av[i], bv[j], acc[i][j]);
    }
  }
#pragma unroll
  for (int i = 0; i < 4; ++i) {
    float4 o; o.x=acc[i][0]; o.y=acc[i][1]; o.z=acc[i][2]; o.w=acc[i][3];
    *(float4*)&P[(r0 + ty*4 + i)*256 + c0 + tx*4] = o;
  }
}

// ---------------------------------------------------------------------------
// c1gather: C1ws[n][i][j]=adj[nb_i,nb_j]; [i][17]=cc1_i; row0[18]=nz-row mask.
// ---------------------------------------------------------------------------
__global__ __launch_bounds__(320) void c1gather(const float* __restrict__ adj,
                                                const int* __restrict__ neighbors,
                                                float* __restrict__ C1ws) {
  __shared__ int nbs[K1];
  __shared__ float c1sh[K1 * K1];
  int n = blockIdx.x;
  int tid = threadIdx.x;
  if (tid < K1) nbs[tid] = (tid == 0) ? n : neighbors[n*KNB + tid - 1];
  __syncthreads();
  if (tid < 289) {
    int i = tid / 17, j = tid % 17;
    float v = adj[nbs[i]*NN + nbs[j]];
    C1ws[n*C1NODE + i*C1STRIDE + j] = v;
    c1sh[tid] = v;
  }
  __syncthreads();
  bool nz = false;
  if (tid < K1) {
    float s = 0.f;
#pragma unroll
    for (int j = 0; j < K1; ++j) {
      float v = c1sh[tid*17 + j];
      s = fmaf(v, v, s); nz |= (v != 0.f);
    }
    C1ws[n*C1NODE + tid*C1STRIDE + 17] = s * (1.f/17.f);
  }
  unsigned long long bal = __ballot(nz);   // only wave 0 has tid<17
  if (tid == 0)
    ((int*)C1ws)[n*C1NODE + 18] = (int)(bal & 0x1FFFF);
}

// ---------------------------------------------------------------------------
// main: 1 block/node, 256 thr = 16 templates x 16 cols. No __syncthreads
// after setup (waves own disjoint template groups).
// ---------------------------------------------------------------------------
__global__ __launch_bounds__(256, 2) void ltfgw_main(
    const float* __restrict__ P, const float* __restrict__ C1ws,
    const float* __restrict__ xsq, const float* __restrict__ tfsq,
    const float* __restrict__ qmat, const float* __restrict__ cq,
    const float* __restrict__ walpha, const int* __restrict__ neighbors,
    const float* __restrict__ templates_, float* __restrict__ out) {
  __shared__ __align__(16) float Ksh[16 * TSTR];   // 18944 B
  __shared__ __align__(16) float Ush[256];
  __shared__ __align__(16) float Vsh[256];

  const int tid = threadIdx.x;
  const int t = tid >> 4, l = tid & 15;
  const int n = blockIdx.x;

  const float alpha = sload(walpha);
  const float oma = 1.f - alpha;
  const float na2 = -2.f * alpha;
  const int mask = sloadi((const int*)C1ws + n*C1NODE + 18);

  int nbk[K1];
  nbk[0] = n;
#pragma unroll
  for (int k = 1; k < K1; ++k) nbk[k] = sloadi(neighbors + n*KNB + (k-1));

  const float tfsq_l = tfsq[tid];
  const float cq_l   = cq[tid];
  const float q_l    = qmat[tid];

  // Mcol = (1-a)*M + a*cC ; grad = Mcol - 2a*(C1@G@C2^T)
  float Mcol[K1];
#pragma unroll
  for (int k = 0; k < K1; ++k) {
    float xs  = sload(xsq + nbk[k]);
    float cc1 = sload(C1ws + n*C1NODE + k*C1STRIDE + 17);
    float pv  = P[nbk[k]*256 + tid];
    Mcol[k] = oma * (xs + tfsq_l - 2.f*pv) + alpha * (cc1 + cq_l);
  }

  // c2reg[r] = -2a * C2[t][l][l^r]  (pre-rotated for the XOR walk)
  float c2reg[16];
#pragma unroll
  for (int r = 0; r < 16; ++r)
    c2reg[r] = na2 * templates_[t*256 + l*16 + (l ^ r)];

  // G[j][l] in registers; init p*q
  float Gcol[K1];
#pragma unroll
  for (int j = 0; j < K1; ++j) Gcol[j] = (1.f/17.f) * q_l;

  const int tb = t * TSTR;
  float ur[16], u16 = 0.f, vm = 1.f;

#pragma unroll 1
  for (int outer = 0; outer < 3; ++outer) {
    // grad rows -> Kc[]; only C1-nonzero rows get the matvec + DPP walk
    float Kc[K1];
    float lo = 3.0e38f, hi = -3.0e38f;
#pragma unroll
    for (int i = 0; i < K1; ++i) {
      float gr = Mcol[i];
      if (mask & (1 << i)) {
        const float* c1r = C1ws + n*C1NODE + i*C1STRIDE;
        float s = 0.f;
#pragma unroll
        for (int j = 0; j < K1; ++j) s = fmaf(sload(c1r + j), Gcol[j], s);
        float g = s, acc = s * c2reg[0];
        WALK15()
        gr += acc;
      }
      Kc[i] = gr;
      lo = fminf(lo, gr); hi = fmaxf(hi, gr);
    }
    lo = rmin16(lo); hi = rmax16(hi);
    float eps = 0.1f * (hi - lo) + TINYF;
    float sc = 1.4426950408889634f * __builtin_amdgcn_rcpf(eps);
#pragma unroll
    for (int i = 0; i < K1; ++i) {
      Kc[i] = __builtin_amdgcn_exp2f((lo - Kc[i]) * sc);
      Ksh[tb + i*17 + l] = Kc[i];           // transpose write (same wave)
    }
    // row l of K for the u-update
    float Krow[16];
#pragma unroll
    for (int jq = 0; jq < 4; ++jq) {
      float4 v = *(const float4*)&Ksh[tb + l*17 + jq*4];
      Krow[jq*4+0]=v.x; Krow[jq*4+1]=v.y; Krow[jq*4+2]=v.z; Krow[jq*4+3]=v.w;
    }

    // Sinkhorn: 5 iters (u then v), v0 = 1
    float vlane = 1.f;
    Vsh[tid] = 1.f;
#pragma unroll 1
    for (int it = 0; it < 5; ++it) {
      float vr[16];
#pragma unroll
      for (int q = 0; q < 4; ++q) {
        float4 v = *(const float4*)&Vsh[t*16 + q*4];
        vr[q*4+0]=v.x; vr[q*4+1]=v.y; vr[q*4+2]=v.z; vr[q*4+3]=v.w;
      }
      float w = 0.f;
#pragma unroll
      for (int j = 0; j < 16; ++j) w = fmaf(Krow[j], vr[j], w);
      float w16 = rsum16(Kc[16] * vlane);          // row 16 via DPP
      float um = (1.f/17.f) * rcpn(fmaxf(w,   TINYF));
      u16      = (1.f/17.f) * rcpn(fmaxf(w16, TINYF));
      Ush[tid] = um;
#pragma unroll
      for (int q = 0; q < 4; ++q) {
        float4 v = *(const float4*)&Ush[t*16 + q*4];
        ur[q*4+0]=v.x; ur[q*4+1]=v.y; ur[q*4+2]=v.z; ur[q*4+3]=v.w;
      }
      float sg = u16 * Kc[16];
#pragma unroll
      for (int k = 0; k < 16; ++k) sg = fmaf(ur[k], Kc[k], sg);
      vlane = q_l * rcpn(fmaxf(sg, TINYF));
      Vsh[tid] = vlane;
    }
    vm = vlane;
    // G = u * K * v
#pragma unroll
    for (int k = 0; k < 16; ++k) Gcol[k] = ur[k] * Kc[k] * vm;
    Gcol[16] = u16 * Kc[16] * vm;
  }

  // out[n,t] = sum_{i,l} (Mcol + delta) * G
  float acc1 = 0.f;
#pragma unroll
  for (int i = 0; i < K1; ++i) acc1 = fmaf(Mcol[i], Gcol[i], acc1);
#pragma unroll
  for (int i = 0; i < K1; ++i) {
    if (mask & (1 << i)) {
      const float* c1r = C1ws + n*C1NODE + i*C1STRIDE;
      float s = 0.f;
#pragma unroll
      for (int j = 0; j < K1; ++j) s = fmaf(sload(c1r + j), Gcol[j], s);
      float g = s, acc = s * c2reg[0];
      WALK15()
      acc1 = fmaf(acc, Gcol[i], acc1);
    }
  }
  float accout = rsum16(acc1);
  if (l == 0) out[n*16 + t] = accout;
}

// ---------------------------------------------------------------------------
extern "C" void kernel_launch(void* const* d_in, const int* in_sizes, int n_in,
                              void* d_out, int out_size, void* d_ws, size_t ws_size,
                              hipStream_t stream) {
  const float* x          = (const float*)d_in[0];
  const float* adj        = (const float*)d_in[1];
  const int*   neighbors  = (const int*)  d_in[2];
  const float* templates_ = (const float*)d_in[3];
  const float* tfeat      = (const float*)d_in[4];
  const float* q0         = (const float*)d_in[5];
  const float* alpha0     = (const float*)d_in[6];
  float* out = (float*)d_out;

  float* ws     = (float*)d_ws;
  float* P      = ws;                       // 4096*256
  float* C1ws   = P + 4096*256;             // 4096*340
  float* xsq    = C1ws + 4096*C1NODE;       // 4096
  float* tfsq   = xsq + 4096;               // 256
  float* qmat   = tfsq + 256;               // 256
  float* cq     = qmat + 256;               // 256
  float* walpha = cq + 256;                 // 1

  hipLaunchKernelGGL(prep_all, dim3(1025), dim3(256), 0, stream,
                     x, q0, templates_, tfeat, alpha0,
                     xsq, qmat, cq, tfsq, walpha);
  hipLaunchKernelGGL(pgemm, dim3(64, 4), dim3(256), 0, stream, x, tfeat, P);
  hipLaunchKernelGGL(c1gather, dim3(4096), dim3(320), 0, stream,
                     adj, neighbors, C1ws);
  hipLaunchKernelGGL(ltfgw_main, dim3(4096), dim3(256), 0, stream,
                     P, C1ws, xsq, tfsq, qmat, cq, walpha, neighbors,
                     templates_, out);
}

// Round 5
// 181.102 us; speedup vs baseline: 2.8218x; 1.0666x over previous
//
#include <hip/hip_runtime.h>
#include <math.h>

// ---------------------------------------------------------------------------
// LTFGW: N=4096, K=16 (k1=17), T=16, NT=16, D=128, OUTER=3, INNER=5.
//
// R5: R4's verified main kernel (scalar-pipe C1, sparsity mask, absmax 0.0)
//     + the three independent producer kernels (pgemm / prep / c1gather)
//     fused into ONE block-range-partitioned dispatch so the memory-latency-
//     bound adj gather overlaps the VALU-bound GEMM instead of serializing.
//     4 dispatches -> 2. Main: exp arg folded to one fma.
// R2/R3 lesson (kept): no LDS vector loads of C1 inside unrolled branches —
// scheduler hoists ~270 VGPRs of ds_read results -> 0.5-1 GB scratch spill.
// ---------------------------------------------------------------------------

#define NN 4096
#define KNB 16
#define K1 17
#define C1STRIDE 20   // C1 row: 17 vals + cc1@17 + mask@18(row0) + pad
#define C1NODE 340
#define TSTR 296      // Ksh per-template stride; 296%32==8 -> 2-way banks
#define TINYF 1e-16f

typedef const __attribute__((address_space(4))) float* c4fp;
typedef const __attribute__((address_space(4))) int*   c4ip;
__device__ __forceinline__ float sload(const float* p){ return *(c4fp)(unsigned long long)p; }
__device__ __forceinline__ int   sloadi(const int* p) { return *(c4ip)(unsigned long long)p; }

template<int CTRL>
__device__ __forceinline__ float dppmov(float x) {
  return __int_as_float(
      __builtin_amdgcn_update_dpp(0, __float_as_int(x), CTRL, 0xF, 0xF, true));
}
__device__ __forceinline__ float xor4v(float x) {        // xor4 = xor7 then xor3
  return dppmov<0x1B>(dppmov<0x141>(x));
}
__device__ __forceinline__ float rsum16(float x) {
  x += dppmov<0xB1>(x); x += dppmov<0x4E>(x);
  x += xor4v(x);        x += dppmov<0x128>(x);
  return x;
}
__device__ __forceinline__ float rmin16(float x) {
  x = fminf(x, dppmov<0xB1>(x)); x = fminf(x, dppmov<0x4E>(x));
  x = fminf(x, xor4v(x));        x = fminf(x, dppmov<0x128>(x));
  return x;
}
__device__ __forceinline__ float rmax16(float x) {
  x = fmaxf(x, dppmov<0xB1>(x)); x = fmaxf(x, dppmov<0x4E>(x));
  x = fmaxf(x, xor4v(x));        x = fmaxf(x, dppmov<0x128>(x));
  return x;
}
__device__ __forceinline__ float rcpn(float x) {   // rcp + 1 Newton step
  float r = __builtin_amdgcn_rcpf(x);
  return r * (2.f - x * r);
}

// cumulative XOR walk (verified R1/R4, absmax 0): after step r, g = src lane l^r
#define WSTEP(C, R) { g = dppmov<C>(g); acc = fmaf(g, c2reg[R], acc); }
#define WALK15() \
  WSTEP(0xB1,1)  WSTEP(0x1B,2)  WSTEP(0xB1,3)  WSTEP(0x141,4) \
  WSTEP(0xB1,5)  WSTEP(0x1B,6)  WSTEP(0xB1,7)  WSTEP(0x140,8) \
  WSTEP(0xB1,9)  WSTEP(0x1B,10) WSTEP(0xB1,11) WSTEP(0x141,12) \
  WSTEP(0xB1,13) WSTEP(0x1B,14) WSTEP(0xB1,15)

// ---------------------------------------------------------------------------
// prep_combined: one dispatch, block-range partitioned.
//   blocks [0,256)        : pgemm  P = x @ tf^T          (VALU-bound)
//   blocks [256,1280)     : xsq[n] = ||x[n]||^2          (trivial)
//   block  1280           : scalars (alpha,q,cq,tfsq)
//   blocks [1281,5377)    : c1gather                     (mem-latency-bound)
// The three groups are independent; fusing lets them co-reside instead of
// serializing through 3 graph nodes (R4: ~121us outside main).
// ---------------------------------------------------------------------------
#define PG_GEMM  256
#define PG_XSQ   (PG_GEMM + 1024)       // 1280
#define PG_SCAL  PG_XSQ                  // block 1280
#define PG_C1    (PG_SCAL + 1)           // 1281
#define PG_TOT   (PG_C1 + 4096)          // 5377

__global__ __launch_bounds__(256) void prep_combined(
    const float* __restrict__ x, const float* __restrict__ adj,
    const int* __restrict__ neighbors, const float* __restrict__ templates_,
    const float* __restrict__ tf, const float* __restrict__ q0,
    const float* __restrict__ alpha0,
    float* __restrict__ P, float* __restrict__ C1ws, float* __restrict__ xsq,
    float* __restrict__ tfsq, float* __restrict__ qmat, float* __restrict__ cq,
    float* __restrict__ walpha) {
  __shared__ __align__(16) float smem[2 * 64 * 68];   // 34816 B arena
  const int b = blockIdx.x, tid = threadIdx.x;

  if (b < PG_GEMM) {
    // ---- pgemm: 64x64 tile, 4x4 per thread ----
    float (*As)[68] = (float (*)[68])smem;
    float (*Bs)[68] = (float (*)[68])(smem + 64 * 68);
    int tx = tid & 15, ty = tid >> 4;
    int r0 = (b & 63) * 64, c0 = (b >> 6) * 64;
    float acc[4][4] = {};
    for (int h = 0; h < 2; ++h) {
      __syncthreads();
#pragma unroll
      for (int q = 0; q < 4; ++q) {
        int f = tid + 256*q;
        int row = f >> 4, d4 = (f & 15) << 2;
        float4 a = *(const float4*)&x[(r0+row)*128 + h*64 + d4];
        As[d4+0][row]=a.x; As[d4+1][row]=a.y; As[d4+2][row]=a.z; As[d4+3][row]=a.w;
        float4 bb = *(const float4*)&tf[(c0+row)*128 + h*64 + d4];
        Bs[d4+0][row]=bb.x; Bs[d4+1][row]=bb.y; Bs[d4+2][row]=bb.z; Bs[d4+3][row]=bb.w;
      }
      __syncthreads();
#pragma unroll
      for (int d = 0; d < 64; ++d) {
        float4 a = *(const float4*)&As[d][ty*4];
        float4 bb = *(const float4*)&Bs[d][tx*4];
        float av[4]={a.x,a.y,a.z,a.w}, bv[4]={bb.x,bb.y,bb.z,bb.w};
#pragma unroll
        for (int i = 0; i < 4; ++i)
#pragma unroll
          for (int j = 0; j < 4; ++j) acc[i][j] = fmaf(av[i], bv[j], acc[i][j]);
      }
    }
#pragma unroll
    for (int i = 0; i < 4; ++i) {
      float4 o; o.x=acc[i][0]; o.y=acc[i][1]; o.z=acc[i][2]; o.w=acc[i][3];
      *(float4*)&P[(r0 + ty*4 + i)*256 + c0 + tx*4] = o;
    }
    return;
  }

  if (b < PG_XSQ) {
    // ---- xsq: 4 rows per block, 1 wave per row ----
    int n = (b - PG_GEMM)*4 + (tid >> 6), lane = tid & 63;
    float2 v = *(const float2*)&x[n*128 + lane*2];
    float s = fmaf(v.x, v.x, v.y*v.y);
    s += __shfl_xor(s,1); s += __shfl_xor(s,2);  s += __shfl_xor(s,4);
    s += __shfl_xor(s,8); s += __shfl_xor(s,16); s += __shfl_xor(s,32);
    if (lane == 0) xsq[n] = s;
    return;
  }

  if (b == PG_SCAL) {
    // ---- scalars: alpha, q=softmax(q0), cq, tfsq ----
    int t = tid >> 4, l = tid & 15;
    if (tid == 0) walpha[0] = 1.f / (1.f + expf(-alpha0[0]));
    float qr[16]; float mx = -3.0e38f;
#pragma unroll
    for (int m = 0; m < 16; ++m) { qr[m] = q0[t*16+m]; mx = fmaxf(mx, qr[m]); }
    float s = 0.f;
#pragma unroll
    for (int m = 0; m < 16; ++m) { qr[m] = expf(qr[m]-mx); s += qr[m]; }
    float inv = 1.f / s;
    qmat[tid] = qr[l] * inv;
    float c = 0.f;
#pragma unroll
    for (int m = 0; m < 16; ++m) {
      float c2 = templates_[t*256 + l*16 + m];
      c = fmaf(qr[m]*inv, c2*c2, c);
    }
    cq[tid] = c;
    float ts = 0.f;
#pragma unroll
    for (int dq = 0; dq < 32; ++dq) {
      float4 v = *(const float4*)&tf[tid*128 + dq*4];
      ts = fmaf(v.x,v.x,ts); ts = fmaf(v.y,v.y,ts);
      ts = fmaf(v.z,v.z,ts); ts = fmaf(v.w,v.w,ts);
    }
    tfsq[tid] = ts;
    return;
  }

  // ---- c1gather: C1ws[n][i][j]=adj[nb_i,nb_j]; cc1@17; nz-row mask@18 ----
  {
    int n = b - PG_C1;
    int*   nbs  = (int*)smem;          // 17 ints
    float* c1sh = smem + 32;           // 289 floats
    if (tid < K1) nbs[tid] = (tid == 0) ? n : neighbors[n*KNB + tid - 1];
    __syncthreads();
    for (int e = tid; e < 289; e += 256) {
      int i = e / 17, j = e % 17;
      float v = adj[nbs[i]*NN + nbs[j]];
      C1ws[n*C1NODE + i*C1STRIDE + j] = v;
      c1sh[e] = v;
    }
    __syncthreads();
    bool nz = false;
    if (tid < K1) {
      float s = 0.f;
#pragma unroll
      for (int j = 0; j < K1; ++j) {
        float v = c1sh[tid*17 + j];
        s = fmaf(v, v, s); nz |= (v != 0.f);
      }
      C1ws[n*C1NODE + tid*C1STRIDE + 17] = s * (1.f/17.f);
    }
    unsigned long long bal = __ballot(nz);   // wave 0 holds tid<17
    if (tid == 0)
      ((int*)C1ws)[n*C1NODE + 18] = (int)(bal & 0x1FFFF);
  }
}

// ---------------------------------------------------------------------------
// main: 1 block/node, 256 thr = 16 templates x 16 cols (R4-verified).
// ---------------------------------------------------------------------------
__global__ __launch_bounds__(256, 2) void ltfgw_main(
    const float* __restrict__ P, const float* __restrict__ C1ws,
    const float* __restrict__ xsq, const float* __restrict__ tfsq,
    const float* __restrict__ qmat, const float* __restrict__ cq,
    const float* __restrict__ walpha, const int* __restrict__ neighbors,
    const float* __restrict__ templates_, float* __restrict__ out) {
  __shared__ __align__(16) float Ksh[16 * TSTR];
  __shared__ __align__(16) float Ush[256];
  __shared__ __align__(16) float Vsh[256];

  const int tid = threadIdx.x;
  const int t = tid >> 4, l = tid & 15;
  const int n = blockIdx.x;

  const float alpha = sload(walpha);
  const float oma = 1.f - alpha;
  const float na2 = -2.f * alpha;
  const int mask = sloadi((const int*)C1ws + n*C1NODE + 18);

  int nbk[K1];
  nbk[0] = n;
#pragma unroll
  for (int k = 1; k < K1; ++k) nbk[k] = sloadi(neighbors + n*KNB + (k-1));

  const float tfsq_l = tfsq[tid];
  const float cq_l   = cq[tid];
  const float q_l    = qmat[tid];

  // Mcol = (1-a)*M + a*cC ; grad = Mcol - 2a*(C1@G@C2^T)
  float Mcol[K1];
#pragma unroll
  for (int k = 0; k < K1; ++k) {
    float xs  = sload(xsq + nbk[k]);
    float cc1 = sload(C1ws + n*C1NODE + k*C1STRIDE + 17);
    float pv  = P[nbk[k]*256 + tid];
    Mcol[k] = oma * (xs + tfsq_l - 2.f*pv) + alpha * (cc1 + cq_l);
  }

  // c2reg[r] = -2a * C2[t][l][l^r]  (pre-rotated for the XOR walk)
  float c2reg[16];
#pragma unroll
  for (int r = 0; r < 16; ++r)
    c2reg[r] = na2 * templates_[t*256 + l*16 + (l ^ r)];

  // G[j][l] in registers; init p*q
  float Gcol[K1];
#pragma unroll
  for (int j = 0; j < K1; ++j) Gcol[j] = (1.f/17.f) * q_l;

  const int tb = t * TSTR;
  float ur[16], u16 = 0.f, vm = 1.f;

#pragma unroll 1
  for (int outer = 0; outer < 3; ++outer) {
    // grad rows -> Kc[]; only C1-nonzero rows get the matvec + DPP walk
    float Kc[K1];
    float lo = 3.0e38f, hi = -3.0e38f;
#pragma unroll
    for (int i = 0; i < K1; ++i) {
      float gr = Mcol[i];
      if (mask & (1 << i)) {
        const float* c1r = C1ws + n*C1NODE + i*C1STRIDE;
        float s = 0.f;
#pragma unroll
        for (int j = 0; j < K1; ++j) s = fmaf(sload(c1r + j), Gcol[j], s);
        float g = s, acc = s * c2reg[0];
        WALK15()
        gr += acc;
      }
      Kc[i] = gr;
      lo = fminf(lo, gr); hi = fmaxf(hi, gr);
    }
    lo = rmin16(lo); hi = rmax16(hi);
    float eps = 0.1f * (hi - lo) + TINYF;
    float sc = 1.4426950408889634f * __builtin_amdgcn_rcpf(eps);
    float nsc = -sc, losc = lo * sc;
#pragma unroll
    for (int i = 0; i < K1; ++i) {
      Kc[i] = __builtin_amdgcn_exp2f(fmaf(Kc[i], nsc, losc));
      Ksh[tb + i*17 + l] = Kc[i];           // transpose write (same wave)
    }
    // row l of K for the u-update
    float Krow[16];
#pragma unroll
    for (int jq = 0; jq < 4; ++jq) {
      float4 v = *(const float4*)&Ksh[tb + l*17 + jq*4];
      Krow[jq*4+0]=v.x; Krow[jq*4+1]=v.y; Krow[jq*4+2]=v.z; Krow[jq*4+3]=v.w;
    }

    // Sinkhorn: 5 iters (u then v), v0 = 1
    float vlane = 1.f;
    Vsh[tid] = 1.f;
#pragma unroll 1
    for (int it = 0; it < 5; ++it) {
      float vr[16];
#pragma unroll
      for (int q = 0; q < 4; ++q) {
        float4 v = *(const float4*)&Vsh[t*16 + q*4];
        vr[q*4+0]=v.x; vr[q*4+1]=v.y; vr[q*4+2]=v.z; vr[q*4+3]=v.w;
      }
      float w = 0.f;
#pragma unroll
      for (int j = 0; j < 16; ++j) w = fmaf(Krow[j], vr[j], w);
      float w16 = rsum16(Kc[16] * vlane);          // row 16 via DPP
      float um = (1.f/17.f) * rcpn(fmaxf(w,   TINYF));
      u16      = (1.f/17.f) * rcpn(fmaxf(w16, TINYF));
      Ush[tid] = um;
#pragma unroll
      for (int q = 0; q < 4; ++q) {
        float4 v = *(const float4*)&Ush[t*16 + q*4];
        ur[q*4+0]=v.x; ur[q*4+1]=v.y; ur[q*4+2]=v.z; ur[q*4+3]=v.w;
      }
      float sg = u16 * Kc[16];
#pragma unroll
      for (int k = 0; k < 16; ++k) sg = fmaf(ur[k], Kc[k], sg);
      vlane = q_l * rcpn(fmaxf(sg, TINYF));
      Vsh[tid] = vlane;
    }
    vm = vlane;
    // G = u * K * v
#pragma unroll
    for (int k = 0; k < 16; ++k) Gcol[k] = ur[k] * Kc[k] * vm;
    Gcol[16] = u16 * Kc[16] * vm;
  }

  // out[n,t] = sum_{i,l} (Mcol + delta) * G
  float acc1 = 0.f;
#pragma unroll
  for (int i = 0; i < K1; ++i) acc1 = fmaf(Mcol[i], Gcol[i], acc1);
#pragma unroll
  for (int i = 0; i < K1; ++i) {
    if (mask & (1 << i)) {
      const float* c1r = C1ws + n*C1NODE + i*C1STRIDE;
      float s = 0.f;
#pragma unroll
      for (int j = 0; j < K1; ++j) s = fmaf(sload(c1r + j), Gcol[j], s);
      float g = s, acc = s * c2reg[0];
      WALK15()
      acc1 = fmaf(acc, Gcol[i], acc1);
    }
  }
  float accout = rsum16(acc1);
  if (l == 0) out[n*16 + t] = accout;
}

// ---------------------------------------------------------------------------
extern "C" void kernel_launch(void* const* d_in, const int* in_sizes, int n_in,
                              void* d_out, int out_size, void* d_ws, size_t ws_size,
                              hipStream_t stream) {
  const float* x          = (const float*)d_in[0];
  const float* adj        = (const float*)d_in[1];
  const int*   neighbors  = (const int*)  d_in[2];
  const float* templates_ = (const float*)d_in[3];
  const float* tfeat      = (const float*)d_in[4];
  const float* q0         = (const float*)d_in[5];
  const float* alpha0     = (const float*)d_in[6];
  float* out = (float*)d_out;

  float* ws     = (float*)d_ws;
  float* P      = ws;                       // 4096*256
  float* C1ws   = P + 4096*256;             // 4096*340
  float* xsq    = C1ws + 4096*C1NODE;       // 4096
  float* tfsq   = xsq + 4096;               // 256
  float* qmat   = tfsq + 256;               // 256
  float* cq     = qmat + 256;               // 256
  float* walpha = cq + 256;                 // 1

  hipLaunchKernelGGL(prep_combined, dim3(PG_TOT), dim3(256), 0, stream,
                     x, adj, neighbors, templates_, tfeat, q0, alpha0,
                     P, C1ws, xsq, tfsq, qmat, cq, walpha);
  hipLaunchKernelGGL(ltfgw_main, dim3(4096), dim3(256), 0, stream,
                     P, C1ws, xsq, tfsq, qmat, cq, walpha, neighbors,
                     templates_, out);
}